// Round 1
// baseline (741.815 us; speedup 1.0000x reference)
//
#include <hip/hip_runtime.h>

#define NB 64
#define SS 512
#define HIDD 256
#define NHEADS 4
#define ADIM 64
#define NEGV (-1e10f)

// ---------------------------------------------------------------------------
// C[M,N] = A[M,K] @ W[K,N] + bias[N]   (fp32, 64x64 tile, K-chunk 16)
// ---------------------------------------------------------------------------
__global__ __launch_bounds__(256) void gemm_bias(
    const float* __restrict__ A, const float* __restrict__ W,
    const float* __restrict__ bias, float* __restrict__ C,
    int M, int K, int N)
{
    __shared__ float As[16][68];   // transposed: As[kk][m], rows 16B-aligned (68*4=272=17*16)
    __shared__ float Ws[16][68];   // Ws[kk][n]
    const int tid = threadIdx.x;
    const int tx = tid & 15, ty = tid >> 4;
    const int bm = blockIdx.x * 64, bn = blockIdx.y * 64;

    float acc[4][4];
#pragma unroll
    for (int i = 0; i < 4; ++i)
#pragma unroll
        for (int j = 0; j < 4; ++j) acc[i][j] = 0.f;

    for (int k0 = 0; k0 < K; k0 += 16) {
        {
            const int m_l = tid >> 2;
            const int kk = (tid & 3) << 2;
            float4 a4 = *reinterpret_cast<const float4*>(&A[(size_t)(bm + m_l) * K + k0 + kk]);
            As[kk + 0][m_l] = a4.x;
            As[kk + 1][m_l] = a4.y;
            As[kk + 2][m_l] = a4.z;
            As[kk + 3][m_l] = a4.w;
            const int k_l = tid >> 4;
            const int n0 = (tid & 15) << 2;
            float4 w4 = *reinterpret_cast<const float4*>(&W[(size_t)(k0 + k_l) * N + bn + n0]);
            *reinterpret_cast<float4*>(&Ws[k_l][n0]) = w4;
        }
        __syncthreads();
#pragma unroll
        for (int kk = 0; kk < 16; ++kk) {
            float4 a = *reinterpret_cast<const float4*>(&As[kk][ty << 2]);
            float4 w = *reinterpret_cast<const float4*>(&Ws[kk][tx << 2]);
            const float av[4] = {a.x, a.y, a.z, a.w};
            const float wv[4] = {w.x, w.y, w.z, w.w};
#pragma unroll
            for (int i = 0; i < 4; ++i)
#pragma unroll
                for (int j = 0; j < 4; ++j)
                    acc[i][j] += av[i] * wv[j];
        }
        __syncthreads();
    }
#pragma unroll
    for (int i = 0; i < 4; ++i) {
        const int m = bm + (ty << 2) + i;
        const int n = bn + (tx << 2);
        float4 o;
        o.x = acc[i][0] + bias[n + 0];
        o.y = acc[i][1] + bias[n + 1];
        o.z = acc[i][2] + bias[n + 2];
        o.w = acc[i][3] + bias[n + 3];
        *reinterpret_cast<float4*>(&C[(size_t)m * N + n]) = o;
    }
}

// ---------------------------------------------------------------------------
// B1: attention[b,q,k] = mean_h softmax_k( mask ? (Q_h . K_h)/8 : -1e10 )
// One block = 32 q-rows of one batch. e[4][16]/thread, 8 qg x 32 kg layout.
// ---------------------------------------------------------------------------
__global__ __launch_bounds__(256) void attn_probs_kernel(
    const float* __restrict__ Qp, const float* __restrict__ Kp,
    const int* __restrict__ mask, float* __restrict__ attn)
{
    __shared__ float QsT[64][36];    // [d][q], rows 144B = 9*16 aligned
    __shared__ float KsT[64][132];   // [d][k within 128-tile], rows 528B = 33*16 aligned
    const int b = blockIdx.x;
    const int q0 = blockIdx.y * 32;
    const int tid = threadIdx.x;
    const int qg = tid >> 5;    // 0..7  (4 q-rows each)
    const int kg = tid & 31;    // 0..31 (4 k-cols per k-tile each)

    float acc[4][16];
#pragma unroll
    for (int i = 0; i < 4; ++i)
#pragma unroll
        for (int t = 0; t < 16; ++t) acc[i][t] = 0.f;

    for (int h = 0; h < NHEADS; ++h) {
        __syncthreads();   // protect QsT/KsT against previous iteration readers
        {
            const float* Qbase = Qp + ((size_t)b * SS + q0) * HIDD + h * ADIM;
#pragma unroll
            for (int r = 0; r < 2; ++r) {
                int idx = tid + (r << 8);
                int q  = idx >> 4;
                int d0 = (idx & 15) << 2;
                float4 v = *reinterpret_cast<const float4*>(&Qbase[(size_t)q * HIDD + d0]);
                QsT[d0 + 0][q] = v.x;
                QsT[d0 + 1][q] = v.y;
                QsT[d0 + 2][q] = v.z;
                QsT[d0 + 3][q] = v.w;
            }
        }
        float e[4][16];
#pragma unroll
        for (int i = 0; i < 4; ++i)
#pragma unroll
            for (int t = 0; t < 16; ++t) e[i][t] = 0.f;

        for (int kt = 0; kt < 4; ++kt) {
            __syncthreads();
            const float* Kbase = Kp + ((size_t)b * SS + (kt << 7)) * HIDD + h * ADIM;
#pragma unroll
            for (int r = 0; r < 8; ++r) {
                int idx = tid + (r << 8);
                int k  = idx >> 4;
                int d0 = (idx & 15) << 2;
                float4 v = *reinterpret_cast<const float4*>(&Kbase[(size_t)k * HIDD + d0]);
                KsT[d0 + 0][k] = v.x;
                KsT[d0 + 1][k] = v.y;
                KsT[d0 + 2][k] = v.z;
                KsT[d0 + 3][k] = v.w;
            }
            __syncthreads();
#pragma unroll 16
            for (int d = 0; d < 64; ++d) {
                float4 qv = *reinterpret_cast<const float4*>(&QsT[d][qg << 2]);
                float4 kv = *reinterpret_cast<const float4*>(&KsT[d][kg << 2]);
                const float qa[4] = {qv.x, qv.y, qv.z, qv.w};
                const float ka[4] = {kv.x, kv.y, kv.z, kv.w};
                if (kt == 0) {
#pragma unroll
                    for (int i = 0; i < 4; ++i)
#pragma unroll
                        for (int j = 0; j < 4; ++j) e[i][0 + j] += qa[i] * ka[j];
                } else if (kt == 1) {
#pragma unroll
                    for (int i = 0; i < 4; ++i)
#pragma unroll
                        for (int j = 0; j < 4; ++j) e[i][4 + j] += qa[i] * ka[j];
                } else if (kt == 2) {
#pragma unroll
                    for (int i = 0; i < 4; ++i)
#pragma unroll
                        for (int j = 0; j < 4; ++j) e[i][8 + j] += qa[i] * ka[j];
                } else {
#pragma unroll
                    for (int i = 0; i < 4; ++i)
#pragma unroll
                        for (int j = 0; j < 4; ++j) e[i][12 + j] += qa[i] * ka[j];
                }
            }
        }

        // scale + mask + softmax(row) + head-mean accumulate
        const float scale = 0.125f;
#pragma unroll
        for (int i = 0; i < 4; ++i) {
            const int q = q0 + (qg << 2) + i;
            const int* mrow = mask + ((size_t)b * SS + q) * SS;
            float m = -3.0e38f;
#pragma unroll
            for (int kt = 0; kt < 4; ++kt) {
                int4 mv = *reinterpret_cast<const int4*>(&mrow[(kt << 7) + (kg << 2)]);
                e[i][(kt << 2) + 0] = mv.x ? e[i][(kt << 2) + 0] * scale : NEGV;
                e[i][(kt << 2) + 1] = mv.y ? e[i][(kt << 2) + 1] * scale : NEGV;
                e[i][(kt << 2) + 2] = mv.z ? e[i][(kt << 2) + 2] * scale : NEGV;
                e[i][(kt << 2) + 3] = mv.w ? e[i][(kt << 2) + 3] * scale : NEGV;
                m = fmaxf(m, fmaxf(fmaxf(e[i][(kt << 2) + 0], e[i][(kt << 2) + 1]),
                                   fmaxf(e[i][(kt << 2) + 2], e[i][(kt << 2) + 3])));
            }
#pragma unroll
            for (int off = 16; off >= 1; off >>= 1)
                m = fmaxf(m, __shfl_xor(m, off, 64));
            float s = 0.f;
#pragma unroll
            for (int t = 0; t < 16; ++t) {
                float p = __expf(e[i][t] - m);
                e[i][t] = p;
                s += p;
            }
#pragma unroll
            for (int off = 16; off >= 1; off >>= 1)
                s += __shfl_xor(s, off, 64);
            const float inv = 0.25f / s;
#pragma unroll
            for (int t = 0; t < 16; ++t)
                acc[i][t] += e[i][t] * inv;
        }
    }

    // write attention tile [32 x 512]
#pragma unroll
    for (int i = 0; i < 4; ++i) {
        const int q = q0 + (qg << 2) + i;
#pragma unroll
        for (int kt = 0; kt < 4; ++kt) {
            float4 o = make_float4(acc[i][(kt << 2) + 0], acc[i][(kt << 2) + 1],
                                   acc[i][(kt << 2) + 2], acc[i][(kt << 2) + 3]);
            *reinterpret_cast<float4*>(&attn[((size_t)b * SS + q) * SS + (kt << 7) + (kg << 2)]) = o;
        }
    }
}

// ---------------------------------------------------------------------------
// B2: out[b,q,:] = (attention[b,q,:] @ V[b]) @ Wh + bh
// One block = 64 q-rows of one batch.
// ---------------------------------------------------------------------------
__global__ __launch_bounds__(256) void attn_out_kernel(
    const float* __restrict__ attn, const float* __restrict__ V,
    const float* __restrict__ Wh, const float* __restrict__ bh,
    float* __restrict__ out)
{
    __shared__ float UsT[64][68];         // [d][q]
    __shared__ float R[64 * 68 * 2];      // phase1: AsT + Vs ; phase2: Whs (aliased)
    float* AsT = R;                       // [64][68]  (kk x q, transposed)
    float* Vs  = R + 64 * 68;             // [64][68]  (kk x d)
    float* Whs = R;                       // [32][260]

    const int b = blockIdx.x;
    const int q0 = blockIdx.y * 64;
    const int tid = threadIdx.x;
    const int tx = tid & 15, ty = tid >> 4;

    // ---- phase 1: T[q][d] = attn_tile @ V ----
    float t_acc[4][4];
#pragma unroll
    for (int i = 0; i < 4; ++i)
#pragma unroll
        for (int j = 0; j < 4; ++j) t_acc[i][j] = 0.f;

    for (int kc = 0; kc < 8; ++kc) {
        __syncthreads();
#pragma unroll
        for (int r = 0; r < 4; ++r) {
            int idx = tid + (r << 8);
            int q   = idx >> 4;
            int k0l = (idx & 15) << 2;
            float4 v = *reinterpret_cast<const float4*>(
                &attn[((size_t)b * SS + q0 + q) * SS + (kc << 6) + k0l]);
            AsT[(k0l + 0) * 68 + q] = v.x;
            AsT[(k0l + 1) * 68 + q] = v.y;
            AsT[(k0l + 2) * 68 + q] = v.z;
            AsT[(k0l + 3) * 68 + q] = v.w;
        }
#pragma unroll
        for (int r = 0; r < 4; ++r) {
            int idx = tid + (r << 8);
            int kk = idx >> 4;
            int d0 = (idx & 15) << 2;
            float4 v = *reinterpret_cast<const float4*>(
                &V[((size_t)b * SS + (kc << 6) + kk) * ADIM + d0]);
            *reinterpret_cast<float4*>(&Vs[kk * 68 + d0]) = v;
        }
        __syncthreads();
#pragma unroll 16
        for (int kk = 0; kk < 64; ++kk) {
            float4 a  = *reinterpret_cast<const float4*>(&AsT[kk * 68 + (ty << 2)]);
            float4 vv = *reinterpret_cast<const float4*>(&Vs[kk * 68 + (tx << 2)]);
            const float aa[4] = {a.x, a.y, a.z, a.w};
            const float va[4] = {vv.x, vv.y, vv.z, vv.w};
#pragma unroll
            for (int i = 0; i < 4; ++i)
#pragma unroll
                for (int j = 0; j < 4; ++j)
                    t_acc[i][j] += aa[i] * va[j];
        }
    }
    __syncthreads();
    // write U^T[d][q]
#pragma unroll
    for (int i = 0; i < 4; ++i)
#pragma unroll
        for (int j = 0; j < 4; ++j)
            UsT[(tx << 2) + j][(ty << 2) + i] = t_acc[i][j];

    // ---- phase 2: out = U @ Wh + bh ----
    // thread covers q = q0 + ty*4+i ; n = jj*64 + tx*4+l  (conflict-free Whs reads)
    float o_acc[4][16];
#pragma unroll
    for (int i = 0; i < 4; ++i)
#pragma unroll
        for (int t = 0; t < 16; ++t) o_acc[i][t] = 0.f;

    for (int dc = 0; dc < 2; ++dc) {
        __syncthreads();   // protects R (AsT/Vs -> Whs) and makes UsT visible
#pragma unroll
        for (int r = 0; r < 8; ++r) {
            int idx = tid + (r << 8);
            int dl = idx >> 6;
            int n0 = (idx & 63) << 2;
            float4 w = *reinterpret_cast<const float4*>(
                &Wh[((size_t)((dc << 5) + dl)) * HIDD + n0]);
            *reinterpret_cast<float4*>(&Whs[dl * 260 + n0]) = w;
        }
        __syncthreads();
#pragma unroll 8
        for (int dl = 0; dl < 32; ++dl) {
            float4 u = *reinterpret_cast<const float4*>(&UsT[(dc << 5) + dl][ty << 2]);
            const float ua[4] = {u.x, u.y, u.z, u.w};
#pragma unroll
            for (int jj = 0; jj < 4; ++jj) {
                float4 w = *reinterpret_cast<const float4*>(&Whs[dl * 260 + (jj << 6) + (tx << 2)]);
                const float wa[4] = {w.x, w.y, w.z, w.w};
#pragma unroll
                for (int i = 0; i < 4; ++i) {
                    o_acc[i][(jj << 2) + 0] += ua[i] * wa[0];
                    o_acc[i][(jj << 2) + 1] += ua[i] * wa[1];
                    o_acc[i][(jj << 2) + 2] += ua[i] * wa[2];
                    o_acc[i][(jj << 2) + 3] += ua[i] * wa[3];
                }
            }
        }
    }

#pragma unroll
    for (int i = 0; i < 4; ++i) {
        const int q = q0 + (ty << 2) + i;
#pragma unroll
        for (int jj = 0; jj < 4; ++jj) {
            const int n = (jj << 6) + (tx << 2);
            float4 bv4 = *reinterpret_cast<const float4*>(&bh[n]);
            float4 o;
            o.x = o_acc[i][(jj << 2) + 0] + bv4.x;
            o.y = o_acc[i][(jj << 2) + 1] + bv4.y;
            o.z = o_acc[i][(jj << 2) + 2] + bv4.z;
            o.w = o_acc[i][(jj << 2) + 3] + bv4.w;
            *reinterpret_cast<float4*>(&out[((size_t)b * SS + q) * HIDD + n]) = o;
        }
    }
}

// ---------------------------------------------------------------------------
extern "C" void kernel_launch(void* const* d_in, const int* in_sizes, int n_in,
                              void* d_out, int out_size, void* d_ws, size_t ws_size,
                              hipStream_t stream)
{
    const float* query = (const float*)d_in[0];
    const float* key   = (const float*)d_in[1];
    const float* value = (const float*)d_in[2];
    const int*   mask  = (const int*)d_in[3];
    const float* Wq = (const float*)d_in[4];
    const float* bq = (const float*)d_in[5];
    const float* Wk = (const float*)d_in[6];
    const float* bk = (const float*)d_in[7];
    const float* Wv = (const float*)d_in[8];
    const float* bv = (const float*)d_in[9];
    const float* Wh = (const float*)d_in[10];
    const float* bh = (const float*)d_in[11];

    float* out  = (float*)d_out;                       // [B,S,HID]
    float* attn = out + (size_t)NB * SS * HIDD;        // [B,S,S]

    float* Qp = (float*)d_ws;                          // [B*S, HID]
    float* Kp = Qp + (size_t)NB * SS * HIDD;           // [B*S, HID]
    float* Vp = Kp + (size_t)NB * SS * HIDD;           // [B*S, ADIM]

    gemm_bias<<<dim3(512, 4), 256, 0, stream>>>(query, Wq, bq, Qp, NB * SS, HIDD, HIDD);
    gemm_bias<<<dim3(512, 4), 256, 0, stream>>>(key,   Wk, bk, Kp, NB * SS, HIDD, HIDD);
    gemm_bias<<<dim3(512, 1), 256, 0, stream>>>(value, Wv, bv, Vp, NB * SS, HIDD, ADIM);
    attn_probs_kernel<<<dim3(64, 16), 256, 0, stream>>>(Qp, Kp, mask, attn);
    attn_out_kernel<<<dim3(64, 8), 256, 0, stream>>>(attn, Vp, Wh, bh, out);
}

// Round 2
// 334.219 us; speedup vs baseline: 2.2195x; 2.2195x over previous
//
#include <hip/hip_runtime.h>

#define NB 64
#define SS 512
#define HIDD 256
#define NHEADS 4
#define ADIM 64

typedef __attribute__((ext_vector_type(8))) short short8v;
typedef __attribute__((ext_vector_type(4))) float f32x4;

#define MFMA16(A, B, C) __builtin_amdgcn_mfma_f32_16x16x32_bf16(A, B, C, 0, 0, 0)

// split fp32 x into bf16 hi + bf16 lo with x ~= hi + lo (error ~2^-17 rel)
__device__ __forceinline__ void bsplit(float x, short& hi, short& lo) {
    unsigned u = __float_as_uint(x);
    unsigned uh = (u + 0x8000u) & 0xFFFF0000u;
    hi = (short)(uh >> 16);
    float r = x - __uint_as_float(uh);
    lo = (short)((__float_as_uint(r) + 0x8000u) >> 16);
}

// ---------------------------------------------------------------------------
// C[M,N] = A[M,K] @ W[K,N] + bias[N]   (fp32, 64x64 tile, K-chunk 16)
// ---------------------------------------------------------------------------
__global__ __launch_bounds__(256) void gemm_bias(
    const float* __restrict__ A, const float* __restrict__ W,
    const float* __restrict__ bias, float* __restrict__ C,
    int M, int K, int N)
{
    __shared__ float As[16][68];
    __shared__ float Ws[16][68];
    const int tid = threadIdx.x;
    const int tx = tid & 15, ty = tid >> 4;
    const int bm = blockIdx.x * 64, bn = blockIdx.y * 64;

    float acc[4][4];
#pragma unroll
    for (int i = 0; i < 4; ++i)
#pragma unroll
        for (int j = 0; j < 4; ++j) acc[i][j] = 0.f;

    for (int k0 = 0; k0 < K; k0 += 16) {
        {
            const int m_l = tid >> 2;
            const int kk = (tid & 3) << 2;
            float4 a4 = *reinterpret_cast<const float4*>(&A[(size_t)(bm + m_l) * K + k0 + kk]);
            As[kk + 0][m_l] = a4.x;
            As[kk + 1][m_l] = a4.y;
            As[kk + 2][m_l] = a4.z;
            As[kk + 3][m_l] = a4.w;
            const int k_l = tid >> 4;
            const int n0 = (tid & 15) << 2;
            float4 w4 = *reinterpret_cast<const float4*>(&W[(size_t)(k0 + k_l) * N + bn + n0]);
            *reinterpret_cast<float4*>(&Ws[k_l][n0]) = w4;
        }
        __syncthreads();
#pragma unroll
        for (int kk = 0; kk < 16; ++kk) {
            float4 a = *reinterpret_cast<const float4*>(&As[kk][ty << 2]);
            float4 w = *reinterpret_cast<const float4*>(&Ws[kk][tx << 2]);
            const float av[4] = {a.x, a.y, a.z, a.w};
            const float wv[4] = {w.x, w.y, w.z, w.w};
#pragma unroll
            for (int i = 0; i < 4; ++i)
#pragma unroll
                for (int j = 0; j < 4; ++j)
                    acc[i][j] += av[i] * wv[j];
        }
        __syncthreads();
    }
#pragma unroll
    for (int i = 0; i < 4; ++i) {
        const int m = bm + (ty << 2) + i;
        const int n = bn + (tx << 2);
        float4 o;
        o.x = acc[i][0] + bias[n + 0];
        o.y = acc[i][1] + bias[n + 1];
        o.z = acc[i][2] + bias[n + 2];
        o.w = acc[i][3] + bias[n + 3];
        *reinterpret_cast<float4*>(&C[(size_t)m * N + n]) = o;
    }
}

// ---------------------------------------------------------------------------
// attn[b,q,k] = mean_h softmax_k( mask ? (Q_h . K_h)/8 : -inf )
// MFMA split-bf16 (3-term). Block = (b, 32 q-rows), 4 waves, k-split by wave.
// E computed transposed: D[row=k][col=q] via mfma(A=K, B=Q).
// ---------------------------------------------------------------------------
__global__ __launch_bounds__(256) void attn_probs_mfma(
    const float* __restrict__ Qp, const float* __restrict__ Kp,
    const int* __restrict__ mask, float* __restrict__ attn)
{
    __shared__ short Khi[128][72];   // 144B rows: conflict-free b128 frag reads
    __shared__ short Klo[128][72];
    __shared__ short Qhi[32][72];
    __shared__ short Qlo[32][72];
    __shared__ float redA[4][2][16];
    __shared__ float redB[4][2][16];

    // bijective XCD swizzle: 1024 blocks = 8 xcds x 128
    const int wg = blockIdx.x;
    const int swz = (wg & 7) * 128 + (wg >> 3);
    const int b = swz >> 4;
    const int q0 = (swz & 15) * 32;

    const int tid = threadIdx.x;
    const int w = tid >> 6;          // wave 0..3 -> k-subtiles {2w, 2w+1} per 128-tile
    const int l = tid & 63;
    const int l15 = l & 15;
    const int lg = l >> 4;

    // ---- pack mask bits: per lane, per qs: 8 frags x 4 k-bits ----
    unsigned mbits[2];
#pragma unroll
    for (int qs = 0; qs < 2; ++qs) {
        unsigned bits = 0;
        const int q = q0 + qs * 16 + l15;
        const int* mrow = mask + ((size_t)b * SS + q) * SS;
#pragma unroll
        for (int f = 0; f < 8; ++f) {
            const int kt = f >> 1, ms = f & 1;
            const int k = kt * 128 + (2 * w + ms) * 16 + lg * 4;
            int4 mv = *reinterpret_cast<const int4*>(&mrow[k]);
            bits |= (mv.x != 0 ? 1u : 0u) << (f * 4 + 0);
            bits |= (mv.y != 0 ? 1u : 0u) << (f * 4 + 1);
            bits |= (mv.z != 0 ? 1u : 0u) << (f * 4 + 2);
            bits |= (mv.w != 0 ? 1u : 0u) << (f * 4 + 3);
        }
        mbits[qs] = bits;
    }

    f32x4 acc[4][2][2];
#pragma unroll
    for (int kt = 0; kt < 4; ++kt)
#pragma unroll
        for (int ms = 0; ms < 2; ++ms)
#pragma unroll
            for (int qs = 0; qs < 2; ++qs)
                acc[kt][ms][qs] = (f32x4){0.f, 0.f, 0.f, 0.f};

    for (int h = 0; h < NHEADS; ++h) {
        __syncthreads();   // previous head's LDS readers done
        // ---- stage Q_h -> Qhi/Qlo ----
        {
            const float* Qb = Qp + ((size_t)b * SS + q0) * HIDD + h * ADIM;
#pragma unroll
            for (int r = 0; r < 2; ++r) {
                const int fid = tid + r * 256;
                const int q = fid >> 4;
                const int d0 = (fid & 15) * 4;
                float4 v = *reinterpret_cast<const float4*>(&Qb[(size_t)q * HIDD + d0]);
                short4 sh, sl;
                bsplit(v.x, sh.x, sl.x);
                bsplit(v.y, sh.y, sl.y);
                bsplit(v.z, sh.z, sl.z);
                bsplit(v.w, sh.w, sl.w);
                *reinterpret_cast<short4*>(&Qhi[q][d0]) = sh;
                *reinterpret_cast<short4*>(&Qlo[q][d0]) = sl;
            }
        }

        f32x4 e[4][2][2];
#pragma unroll
        for (int kt = 0; kt < 4; ++kt)
#pragma unroll
            for (int ms = 0; ms < 2; ++ms)
#pragma unroll
                for (int qs = 0; qs < 2; ++qs)
                    e[kt][ms][qs] = (f32x4){0.f, 0.f, 0.f, 0.f};

#pragma unroll
        for (int kt = 0; kt < 4; ++kt) {
            if (kt > 0) __syncthreads();   // previous tile's frag readers done
            // ---- stage K tile [128][64] -> Khi/Klo ----
            {
                const float* Kb = Kp + ((size_t)b * SS + kt * 128) * HIDD + h * ADIM;
#pragma unroll
                for (int r = 0; r < 8; ++r) {
                    const int fid = tid + r * 256;
                    const int k = fid >> 4;
                    const int d0 = (fid & 15) * 4;
                    float4 v = *reinterpret_cast<const float4*>(&Kb[(size_t)k * HIDD + d0]);
                    short4 sh, sl;
                    bsplit(v.x, sh.x, sl.x);
                    bsplit(v.y, sh.y, sl.y);
                    bsplit(v.z, sh.z, sl.z);
                    bsplit(v.w, sh.w, sl.w);
                    *reinterpret_cast<short4*>(&Khi[k][d0]) = sh;
                    *reinterpret_cast<short4*>(&Klo[k][d0]) = sl;
                }
            }
            __syncthreads();
            // ---- MFMA: E^T tile, split-3 ----
#pragma unroll
            for (int ks2 = 0; ks2 < 2; ++ks2) {
                const int dofs = ks2 * 32 + lg * 8;
                short8v ah0 = *reinterpret_cast<const short8v*>(&Khi[(2 * w + 0) * 16 + l15][dofs]);
                short8v ah1 = *reinterpret_cast<const short8v*>(&Khi[(2 * w + 1) * 16 + l15][dofs]);
                short8v al0 = *reinterpret_cast<const short8v*>(&Klo[(2 * w + 0) * 16 + l15][dofs]);
                short8v al1 = *reinterpret_cast<const short8v*>(&Klo[(2 * w + 1) * 16 + l15][dofs]);
                short8v bh0 = *reinterpret_cast<const short8v*>(&Qhi[l15][dofs]);
                short8v bh1 = *reinterpret_cast<const short8v*>(&Qhi[16 + l15][dofs]);
                short8v bl0 = *reinterpret_cast<const short8v*>(&Qlo[l15][dofs]);
                short8v bl1 = *reinterpret_cast<const short8v*>(&Qlo[16 + l15][dofs]);

                e[kt][0][0] = MFMA16(ah0, bh0, e[kt][0][0]);
                e[kt][0][0] = MFMA16(ah0, bl0, e[kt][0][0]);
                e[kt][0][0] = MFMA16(al0, bh0, e[kt][0][0]);

                e[kt][0][1] = MFMA16(ah0, bh1, e[kt][0][1]);
                e[kt][0][1] = MFMA16(ah0, bl1, e[kt][0][1]);
                e[kt][0][1] = MFMA16(al0, bh1, e[kt][0][1]);

                e[kt][1][0] = MFMA16(ah1, bh0, e[kt][1][0]);
                e[kt][1][0] = MFMA16(ah1, bl0, e[kt][1][0]);
                e[kt][1][0] = MFMA16(al1, bh0, e[kt][1][0]);

                e[kt][1][1] = MFMA16(ah1, bh1, e[kt][1][1]);
                e[kt][1][1] = MFMA16(ah1, bl1, e[kt][1][1]);
                e[kt][1][1] = MFMA16(al1, bh1, e[kt][1][1]);
            }
        }

        // ---- softmax over k (512) per q-row ----
        float mx[2];
#pragma unroll
        for (int qs = 0; qs < 2; ++qs) {
            float m = -3.0e38f;
#pragma unroll
            for (int kt = 0; kt < 4; ++kt)
#pragma unroll
                for (int ms = 0; ms < 2; ++ms)
#pragma unroll
                    for (int r = 0; r < 4; ++r)
                        m = fmaxf(m, e[kt][ms][qs][r]);
            m = fmaxf(m, __shfl_xor(m, 16));
            m = fmaxf(m, __shfl_xor(m, 32));
            mx[qs] = m;
        }
        if (l < 16) { redA[w][0][l] = mx[0]; redA[w][1][l] = mx[1]; }
        __syncthreads();
#pragma unroll
        for (int qs = 0; qs < 2; ++qs)
            mx[qs] = fmaxf(fmaxf(redA[0][qs][l15], redA[1][qs][l15]),
                           fmaxf(redA[2][qs][l15], redA[3][qs][l15]));

        float sm[2] = {0.f, 0.f};
        const float c = 0.125f;
#pragma unroll
        for (int kt = 0; kt < 4; ++kt)
#pragma unroll
            for (int ms = 0; ms < 2; ++ms)
#pragma unroll
                for (int qs = 0; qs < 2; ++qs)
#pragma unroll
                    for (int r = 0; r < 4; ++r) {
                        float p = __expf((e[kt][ms][qs][r] - mx[qs]) * c);
                        const unsigned bit = (mbits[qs] >> ((kt * 2 + ms) * 4 + r)) & 1u;
                        p = bit ? p : 0.f;
                        e[kt][ms][qs][r] = p;
                        sm[qs] += p;
                    }
#pragma unroll
        for (int qs = 0; qs < 2; ++qs) {
            sm[qs] += __shfl_xor(sm[qs], 16);
            sm[qs] += __shfl_xor(sm[qs], 32);
        }
        if (l < 16) { redB[w][0][l] = sm[0]; redB[w][1][l] = sm[1]; }
        __syncthreads();
#pragma unroll
        for (int qs = 0; qs < 2; ++qs) {
            const float Z = (redB[0][qs][l15] + redB[1][qs][l15]) +
                            (redB[2][qs][l15] + redB[3][qs][l15]);
            const float inv = 0.25f / Z;
#pragma unroll
            for (int kt = 0; kt < 4; ++kt)
#pragma unroll
                for (int ms = 0; ms < 2; ++ms)
#pragma unroll
                    for (int r = 0; r < 4; ++r)
                        acc[kt][ms][qs][r] += e[kt][ms][qs][r] * inv;
        }
    }

    // ---- write attention tile ----
#pragma unroll
    for (int kt = 0; kt < 4; ++kt)
#pragma unroll
        for (int ms = 0; ms < 2; ++ms)
#pragma unroll
            for (int qs = 0; qs < 2; ++qs) {
                const int q = q0 + qs * 16 + l15;
                const int k = kt * 128 + (2 * w + ms) * 16 + lg * 4;
                float4 o;
                o.x = acc[kt][ms][qs][0];
                o.y = acc[kt][ms][qs][1];
                o.z = acc[kt][ms][qs][2];
                o.w = acc[kt][ms][qs][3];
                *reinterpret_cast<float4*>(&attn[((size_t)b * SS + q) * SS + k]) = o;
            }
}

// ---------------------------------------------------------------------------
// B2: out[b,q,:] = (attention[b,q,:] @ V[b]) @ Wh + bh
// ---------------------------------------------------------------------------
__global__ __launch_bounds__(256) void attn_out_kernel(
    const float* __restrict__ attn, const float* __restrict__ V,
    const float* __restrict__ Wh, const float* __restrict__ bh,
    float* __restrict__ out)
{
    __shared__ float UsT[64][68];
    __shared__ float R[64 * 68 * 2];
    float* AsT = R;
    float* Vs  = R + 64 * 68;
    float* Whs = R;

    const int b = blockIdx.x;
    const int q0 = blockIdx.y * 64;
    const int tid = threadIdx.x;
    const int tx = tid & 15, ty = tid >> 4;

    float t_acc[4][4];
#pragma unroll
    for (int i = 0; i < 4; ++i)
#pragma unroll
        for (int j = 0; j < 4; ++j) t_acc[i][j] = 0.f;

    for (int kc = 0; kc < 8; ++kc) {
        __syncthreads();
#pragma unroll
        for (int r = 0; r < 4; ++r) {
            int idx = tid + (r << 8);
            int q   = idx >> 4;
            int k0l = (idx & 15) << 2;
            float4 v = *reinterpret_cast<const float4*>(
                &attn[((size_t)b * SS + q0 + q) * SS + (kc << 6) + k0l]);
            AsT[(k0l + 0) * 68 + q] = v.x;
            AsT[(k0l + 1) * 68 + q] = v.y;
            AsT[(k0l + 2) * 68 + q] = v.z;
            AsT[(k0l + 3) * 68 + q] = v.w;
        }
#pragma unroll
        for (int r = 0; r < 4; ++r) {
            int idx = tid + (r << 8);
            int kk = idx >> 4;
            int d0 = (idx & 15) << 2;
            float4 v = *reinterpret_cast<const float4*>(
                &V[((size_t)b * SS + (kc << 6) + kk) * ADIM + d0]);
            *reinterpret_cast<float4*>(&Vs[kk * 68 + d0]) = v;
        }
        __syncthreads();
#pragma unroll 16
        for (int kk = 0; kk < 64; ++kk) {
            float4 a  = *reinterpret_cast<const float4*>(&AsT[kk * 68 + (ty << 2)]);
            float4 vv = *reinterpret_cast<const float4*>(&Vs[kk * 68 + (tx << 2)]);
            const float aa[4] = {a.x, a.y, a.z, a.w};
            const float va[4] = {vv.x, vv.y, vv.z, vv.w};
#pragma unroll
            for (int i = 0; i < 4; ++i)
#pragma unroll
                for (int j = 0; j < 4; ++j)
                    t_acc[i][j] += aa[i] * va[j];
        }
    }
    __syncthreads();
#pragma unroll
    for (int i = 0; i < 4; ++i)
#pragma unroll
        for (int j = 0; j < 4; ++j)
            UsT[(tx << 2) + j][(ty << 2) + i] = t_acc[i][j];

    float o_acc[4][16];
#pragma unroll
    for (int i = 0; i < 4; ++i)
#pragma unroll
        for (int t = 0; t < 16; ++t) o_acc[i][t] = 0.f;

    for (int dc = 0; dc < 2; ++dc) {
        __syncthreads();
#pragma unroll
        for (int r = 0; r < 8; ++r) {
            int idx = tid + (r << 8);
            int dl = idx >> 6;
            int n0 = (idx & 63) << 2;
            float4 w = *reinterpret_cast<const float4*>(
                &Wh[((size_t)((dc << 5) + dl)) * HIDD + n0]);
            *reinterpret_cast<float4*>(&Whs[dl * 260 + n0]) = w;
        }
        __syncthreads();
#pragma unroll 8
        for (int dl = 0; dl < 32; ++dl) {
            float4 u = *reinterpret_cast<const float4*>(&UsT[(dc << 5) + dl][ty << 2]);
            const float ua[4] = {u.x, u.y, u.z, u.w};
#pragma unroll
            for (int jj = 0; jj < 4; ++jj) {
                float4 w = *reinterpret_cast<const float4*>(&Whs[dl * 260 + (jj << 6) + (tx << 2)]);
                const float wa[4] = {w.x, w.y, w.z, w.w};
#pragma unroll
                for (int i = 0; i < 4; ++i) {
                    o_acc[i][(jj << 2) + 0] += ua[i] * wa[0];
                    o_acc[i][(jj << 2) + 1] += ua[i] * wa[1];
                    o_acc[i][(jj << 2) + 2] += ua[i] * wa[2];
                    o_acc[i][(jj << 2) + 3] += ua[i] * wa[3];
                }
            }
        }
    }

#pragma unroll
    for (int i = 0; i < 4; ++i) {
        const int q = q0 + (ty << 2) + i;
#pragma unroll
        for (int jj = 0; jj < 4; ++jj) {
            const int n = (jj << 6) + (tx << 2);
            float4 bv4 = *reinterpret_cast<const float4*>(&bh[n]);
            float4 o;
            o.x = o_acc[i][(jj << 2) + 0] + bv4.x;
            o.y = o_acc[i][(jj << 2) + 1] + bv4.y;
            o.z = o_acc[i][(jj << 2) + 2] + bv4.z;
            o.w = o_acc[i][(jj << 2) + 3] + bv4.w;
            *reinterpret_cast<float4*>(&out[((size_t)b * SS + q) * HIDD + n]) = o;
        }
    }
}

// ---------------------------------------------------------------------------
extern "C" void kernel_launch(void* const* d_in, const int* in_sizes, int n_in,
                              void* d_out, int out_size, void* d_ws, size_t ws_size,
                              hipStream_t stream)
{
    const float* query = (const float*)d_in[0];
    const float* key   = (const float*)d_in[1];
    const float* value = (const float*)d_in[2];
    const int*   mask  = (const int*)d_in[3];
    const float* Wq = (const float*)d_in[4];
    const float* bq = (const float*)d_in[5];
    const float* Wk = (const float*)d_in[6];
    const float* bk = (const float*)d_in[7];
    const float* Wv = (const float*)d_in[8];
    const float* bv = (const float*)d_in[9];
    const float* Wh = (const float*)d_in[10];
    const float* bh = (const float*)d_in[11];

    float* out  = (float*)d_out;                       // [B,S,HID]
    float* attn = out + (size_t)NB * SS * HIDD;        // [B,S,S]

    float* Qp = (float*)d_ws;                          // [B*S, HID]
    float* Kp = Qp + (size_t)NB * SS * HIDD;           // [B*S, HID]
    float* Vp = Kp + (size_t)NB * SS * HIDD;           // [B*S, ADIM]

    gemm_bias<<<dim3(512, 4), 256, 0, stream>>>(query, Wq, bq, Qp, NB * SS, HIDD, HIDD);
    gemm_bias<<<dim3(512, 4), 256, 0, stream>>>(key,   Wk, bk, Kp, NB * SS, HIDD, HIDD);
    gemm_bias<<<dim3(512, 1), 256, 0, stream>>>(value, Wv, bv, Vp, NB * SS, HIDD, ADIM);
    attn_probs_mfma<<<dim3(1024), 256, 0, stream>>>(Qp, Kp, mask, attn);
    attn_out_kernel<<<dim3(64, 8), 256, 0, stream>>>(attn, Vp, Wh, bh, out);
}

// Round 3
// 301.279 us; speedup vs baseline: 2.4622x; 1.1093x over previous
//
#include <hip/hip_runtime.h>

#define NB 64
#define SS 512
#define HIDD 256
#define NHEADS 4
#define ADIM 64

typedef __attribute__((ext_vector_type(8))) short short8v;
typedef __attribute__((ext_vector_type(4))) float f32x4;

#define MFMA16(A, B, C) __builtin_amdgcn_mfma_f32_16x16x32_bf16(A, B, C, 0, 0, 0)

// split fp32 x into bf16 hi + bf16 lo with x ~= hi + lo (error ~2^-17 rel)
__device__ __forceinline__ void bsplit(float x, short& hi, short& lo) {
    unsigned u = __float_as_uint(x);
    unsigned uh = (u + 0x8000u) & 0xFFFF0000u;
    hi = (short)(uh >> 16);
    float r = x - __uint_as_float(uh);
    lo = (short)((__float_as_uint(r) + 0x8000u) >> 16);
}

// ---------------------------------------------------------------------------
// C[M,N] = A[M,K] @ W[K,N] + bias[N]   (fp32, 64x64 tile, K-chunk 16)
// ---------------------------------------------------------------------------
__global__ __launch_bounds__(256) void gemm_bias(
    const float* __restrict__ A, const float* __restrict__ W,
    const float* __restrict__ bias, float* __restrict__ C,
    int M, int K, int N)
{
    __shared__ float As[16][68];
    __shared__ float Ws[16][68];
    const int tid = threadIdx.x;
    const int tx = tid & 15, ty = tid >> 4;
    const int bm = blockIdx.x * 64, bn = blockIdx.y * 64;

    float acc[4][4];
#pragma unroll
    for (int i = 0; i < 4; ++i)
#pragma unroll
        for (int j = 0; j < 4; ++j) acc[i][j] = 0.f;

    for (int k0 = 0; k0 < K; k0 += 16) {
        {
            const int m_l = tid >> 2;
            const int kk = (tid & 3) << 2;
            float4 a4 = *reinterpret_cast<const float4*>(&A[(size_t)(bm + m_l) * K + k0 + kk]);
            As[kk + 0][m_l] = a4.x;
            As[kk + 1][m_l] = a4.y;
            As[kk + 2][m_l] = a4.z;
            As[kk + 3][m_l] = a4.w;
            const int k_l = tid >> 4;
            const int n0 = (tid & 15) << 2;
            float4 w4 = *reinterpret_cast<const float4*>(&W[(size_t)(k0 + k_l) * N + bn + n0]);
            *reinterpret_cast<float4*>(&Ws[k_l][n0]) = w4;
        }
        __syncthreads();
#pragma unroll
        for (int kk = 0; kk < 16; ++kk) {
            float4 a = *reinterpret_cast<const float4*>(&As[kk][ty << 2]);
            float4 w = *reinterpret_cast<const float4*>(&Ws[kk][tx << 2]);
            const float av[4] = {a.x, a.y, a.z, a.w};
            const float wv[4] = {w.x, w.y, w.z, w.w};
#pragma unroll
            for (int i = 0; i < 4; ++i)
#pragma unroll
                for (int j = 0; j < 4; ++j)
                    acc[i][j] += av[i] * wv[j];
        }
        __syncthreads();
    }
#pragma unroll
    for (int i = 0; i < 4; ++i) {
        const int m = bm + (ty << 2) + i;
        const int n = bn + (tx << 2);
        float4 o;
        o.x = acc[i][0] + bias[n + 0];
        o.y = acc[i][1] + bias[n + 1];
        o.z = acc[i][2] + bias[n + 2];
        o.w = acc[i][3] + bias[n + 3];
        *reinterpret_cast<float4*>(&C[(size_t)m * N + n]) = o;
    }
}

// ---------------------------------------------------------------------------
// Same GEMM, epilogue writes bf16 hi/lo split instead of fp32.
// ---------------------------------------------------------------------------
__global__ __launch_bounds__(256) void gemm_bias_split(
    const float* __restrict__ A, const float* __restrict__ W,
    const float* __restrict__ bias, short* __restrict__ Chi,
    short* __restrict__ Clo, int M, int K, int N)
{
    __shared__ float As[16][68];
    __shared__ float Ws[16][68];
    const int tid = threadIdx.x;
    const int tx = tid & 15, ty = tid >> 4;
    const int bm = blockIdx.x * 64, bn = blockIdx.y * 64;

    float acc[4][4];
#pragma unroll
    for (int i = 0; i < 4; ++i)
#pragma unroll
        for (int j = 0; j < 4; ++j) acc[i][j] = 0.f;

    for (int k0 = 0; k0 < K; k0 += 16) {
        {
            const int m_l = tid >> 2;
            const int kk = (tid & 3) << 2;
            float4 a4 = *reinterpret_cast<const float4*>(&A[(size_t)(bm + m_l) * K + k0 + kk]);
            As[kk + 0][m_l] = a4.x;
            As[kk + 1][m_l] = a4.y;
            As[kk + 2][m_l] = a4.z;
            As[kk + 3][m_l] = a4.w;
            const int k_l = tid >> 4;
            const int n0 = (tid & 15) << 2;
            float4 w4 = *reinterpret_cast<const float4*>(&W[(size_t)(k0 + k_l) * N + bn + n0]);
            *reinterpret_cast<float4*>(&Ws[k_l][n0]) = w4;
        }
        __syncthreads();
#pragma unroll
        for (int kk = 0; kk < 16; ++kk) {
            float4 a = *reinterpret_cast<const float4*>(&As[kk][ty << 2]);
            float4 w = *reinterpret_cast<const float4*>(&Ws[kk][tx << 2]);
            const float av[4] = {a.x, a.y, a.z, a.w};
            const float wv[4] = {w.x, w.y, w.z, w.w};
#pragma unroll
            for (int i = 0; i < 4; ++i)
#pragma unroll
                for (int j = 0; j < 4; ++j)
                    acc[i][j] += av[i] * wv[j];
        }
        __syncthreads();
    }
#pragma unroll
    for (int i = 0; i < 4; ++i) {
        const int m = bm + (ty << 2) + i;
        const int n = bn + (tx << 2);
        short4 sh, sl;
        float v0 = acc[i][0] + bias[n + 0];
        float v1 = acc[i][1] + bias[n + 1];
        float v2 = acc[i][2] + bias[n + 2];
        float v3 = acc[i][3] + bias[n + 3];
        bsplit(v0, sh.x, sl.x);
        bsplit(v1, sh.y, sl.y);
        bsplit(v2, sh.z, sl.z);
        bsplit(v3, sh.w, sl.w);
        *reinterpret_cast<short4*>(&Chi[(size_t)m * N + n]) = sh;
        *reinterpret_cast<short4*>(&Clo[(size_t)m * N + n]) = sl;
    }
}

// ---------------------------------------------------------------------------
// attn[b,q,k] = mean_h softmax_k( mask ? (Q_h . K_h)/8 : -inf )
// MFMA split-bf16 (3-term), fragments loaded DIRECTLY global->reg (K/Q are
// L2-resident bf16; no LDS staging, no staging barriers). Block = (b, 32 q),
// 4 waves partition k. E transposed: D[row=k][col=q] via mfma(A=K, B=Q).
// ---------------------------------------------------------------------------
__global__ __launch_bounds__(256) void attn_probs_mfma(
    const short* __restrict__ Qhi_g, const short* __restrict__ Qlo_g,
    const short* __restrict__ Khi_g, const short* __restrict__ Klo_g,
    const int* __restrict__ mask, float* __restrict__ attn)
{
    __shared__ float redA[4][2][16];
    __shared__ float redB[4][2][16];

    // bijective XCD swizzle: 1024 blocks = 8 xcds x 128
    const int wg = blockIdx.x;
    const int swz = (wg & 7) * 128 + (wg >> 3);
    const int b = swz >> 4;
    const int q0 = (swz & 15) * 32;

    const int tid = threadIdx.x;
    const int w = tid >> 6;          // wave 0..3 -> k-subtiles {2w, 2w+1} per 128-tile
    const int l = tid & 63;
    const int l15 = l & 15;
    const int lg = l >> 4;

    // ---- pack mask bits: per lane, per qs: 8 frags x 4 k-bits ----
    unsigned mbits[2];
#pragma unroll
    for (int qs = 0; qs < 2; ++qs) {
        unsigned bits = 0;
        const int q = q0 + qs * 16 + l15;
        const int* mrow = mask + ((size_t)b * SS + q) * SS;
#pragma unroll
        for (int f = 0; f < 8; ++f) {
            const int kt = f >> 1, ms = f & 1;
            const int k = kt * 128 + (2 * w + ms) * 16 + lg * 4;
            int4 mv = *reinterpret_cast<const int4*>(&mrow[k]);
            bits |= (mv.x != 0 ? 1u : 0u) << (f * 4 + 0);
            bits |= (mv.y != 0 ? 1u : 0u) << (f * 4 + 1);
            bits |= (mv.z != 0 ? 1u : 0u) << (f * 4 + 2);
            bits |= (mv.w != 0 ? 1u : 0u) << (f * 4 + 3);
        }
        mbits[qs] = bits;
    }

    f32x4 acc[4][2][2];
#pragma unroll
    for (int kt = 0; kt < 4; ++kt)
#pragma unroll
        for (int ms = 0; ms < 2; ++ms)
#pragma unroll
            for (int qs = 0; qs < 2; ++qs)
                acc[kt][ms][qs] = (f32x4){0.f, 0.f, 0.f, 0.f};

    for (int h = 0; h < NHEADS; ++h) {
        // ---- Q fragments: direct global->reg, reused across all 4 k-tiles ----
        short8v qh[2][2], ql[2][2];
#pragma unroll
        for (int ks2 = 0; ks2 < 2; ++ks2)
#pragma unroll
            for (int qs = 0; qs < 2; ++qs) {
                const int off = (b * SS + q0 + qs * 16 + l15) * HIDD +
                                h * ADIM + ks2 * 32 + lg * 8;
                qh[ks2][qs] = *reinterpret_cast<const short8v*>(Qhi_g + off);
                ql[ks2][qs] = *reinterpret_cast<const short8v*>(Qlo_g + off);
            }

        f32x4 e[4][2][2];
#pragma unroll
        for (int kt = 0; kt < 4; ++kt)
#pragma unroll
            for (int ms = 0; ms < 2; ++ms)
#pragma unroll
                for (int qs = 0; qs < 2; ++qs)
                    e[kt][ms][qs] = (f32x4){0.f, 0.f, 0.f, 0.f};

#pragma unroll
        for (int kt = 0; kt < 4; ++kt) {
#pragma unroll
            for (int ks2 = 0; ks2 < 2; ++ks2) {
                const int rbase = (b * SS + kt * 128 + 2 * w * 16 + l15) * HIDD +
                                  h * ADIM + ks2 * 32 + lg * 8;
                short8v ah0 = *reinterpret_cast<const short8v*>(Khi_g + rbase);
                short8v ah1 = *reinterpret_cast<const short8v*>(Khi_g + rbase + 16 * HIDD);
                short8v al0 = *reinterpret_cast<const short8v*>(Klo_g + rbase);
                short8v al1 = *reinterpret_cast<const short8v*>(Klo_g + rbase + 16 * HIDD);

                e[kt][0][0] = MFMA16(ah0, qh[ks2][0], e[kt][0][0]);
                e[kt][0][0] = MFMA16(ah0, ql[ks2][0], e[kt][0][0]);
                e[kt][0][0] = MFMA16(al0, qh[ks2][0], e[kt][0][0]);

                e[kt][0][1] = MFMA16(ah0, qh[ks2][1], e[kt][0][1]);
                e[kt][0][1] = MFMA16(ah0, ql[ks2][1], e[kt][0][1]);
                e[kt][0][1] = MFMA16(al0, qh[ks2][1], e[kt][0][1]);

                e[kt][1][0] = MFMA16(ah1, qh[ks2][0], e[kt][1][0]);
                e[kt][1][0] = MFMA16(ah1, ql[ks2][0], e[kt][1][0]);
                e[kt][1][0] = MFMA16(al1, qh[ks2][0], e[kt][1][0]);

                e[kt][1][1] = MFMA16(ah1, qh[ks2][1], e[kt][1][1]);
                e[kt][1][1] = MFMA16(ah1, ql[ks2][1], e[kt][1][1]);
                e[kt][1][1] = MFMA16(al1, qh[ks2][1], e[kt][1][1]);
            }
        }

        // ---- softmax over k (512) per q-row ----
        float mx[2];
#pragma unroll
        for (int qs = 0; qs < 2; ++qs) {
            float m = -3.0e38f;
#pragma unroll
            for (int kt = 0; kt < 4; ++kt)
#pragma unroll
                for (int ms = 0; ms < 2; ++ms)
#pragma unroll
                    for (int r = 0; r < 4; ++r)
                        m = fmaxf(m, e[kt][ms][qs][r]);
            m = fmaxf(m, __shfl_xor(m, 16));
            m = fmaxf(m, __shfl_xor(m, 32));
            mx[qs] = m;
        }
        if (l < 16) { redA[w][0][l] = mx[0]; redA[w][1][l] = mx[1]; }
        __syncthreads();
#pragma unroll
        for (int qs = 0; qs < 2; ++qs)
            mx[qs] = fmaxf(fmaxf(redA[0][qs][l15], redA[1][qs][l15]),
                           fmaxf(redA[2][qs][l15], redA[3][qs][l15]));

        float sm[2] = {0.f, 0.f};
        const float c = 0.125f;
#pragma unroll
        for (int kt = 0; kt < 4; ++kt)
#pragma unroll
            for (int ms = 0; ms < 2; ++ms)
#pragma unroll
                for (int qs = 0; qs < 2; ++qs)
#pragma unroll
                    for (int r = 0; r < 4; ++r) {
                        float p = __expf((e[kt][ms][qs][r] - mx[qs]) * c);
                        const unsigned bit = (mbits[qs] >> ((kt * 2 + ms) * 4 + r)) & 1u;
                        p = bit ? p : 0.f;
                        e[kt][ms][qs][r] = p;
                        sm[qs] += p;
                    }
#pragma unroll
        for (int qs = 0; qs < 2; ++qs) {
            sm[qs] += __shfl_xor(sm[qs], 16);
            sm[qs] += __shfl_xor(sm[qs], 32);
        }
        if (l < 16) { redB[w][0][l] = sm[0]; redB[w][1][l] = sm[1]; }
        __syncthreads();
#pragma unroll
        for (int qs = 0; qs < 2; ++qs) {
            const float Z = (redB[0][qs][l15] + redB[1][qs][l15]) +
                            (redB[2][qs][l15] + redB[3][qs][l15]);
            const float inv = 0.25f / Z;
#pragma unroll
            for (int kt = 0; kt < 4; ++kt)
#pragma unroll
                for (int ms = 0; ms < 2; ++ms)
#pragma unroll
                    for (int r = 0; r < 4; ++r)
                        acc[kt][ms][qs][r] += e[kt][ms][qs][r] * inv;
        }
    }

    // ---- write attention tile ----
#pragma unroll
    for (int kt = 0; kt < 4; ++kt)
#pragma unroll
        for (int ms = 0; ms < 2; ++ms)
#pragma unroll
            for (int qs = 0; qs < 2; ++qs) {
                const int q = q0 + qs * 16 + l15;
                const int k = kt * 128 + (2 * w + ms) * 16 + lg * 4;
                float4 o;
                o.x = acc[kt][ms][qs][0];
                o.y = acc[kt][ms][qs][1];
                o.z = acc[kt][ms][qs][2];
                o.w = acc[kt][ms][qs][3];
                *reinterpret_cast<float4*>(&attn[((size_t)b * SS + q) * SS + k]) = o;
            }
}

// ---------------------------------------------------------------------------
// B2: out[b,q,:] = (attention[b,q,:] @ V[b]) @ Wh + bh
// ---------------------------------------------------------------------------
__global__ __launch_bounds__(256) void attn_out_kernel(
    const float* __restrict__ attn, const float* __restrict__ V,
    const float* __restrict__ Wh, const float* __restrict__ bh,
    float* __restrict__ out)
{
    __shared__ float UsT[64][68];
    __shared__ float R[64 * 68 * 2];
    float* AsT = R;
    float* Vs  = R + 64 * 68;
    float* Whs = R;

    const int b = blockIdx.x;
    const int q0 = blockIdx.y * 64;
    const int tid = threadIdx.x;
    const int tx = tid & 15, ty = tid >> 4;

    float t_acc[4][4];
#pragma unroll
    for (int i = 0; i < 4; ++i)
#pragma unroll
        for (int j = 0; j < 4; ++j) t_acc[i][j] = 0.f;

    for (int kc = 0; kc < 8; ++kc) {
        __syncthreads();
#pragma unroll
        for (int r = 0; r < 4; ++r) {
            int idx = tid + (r << 8);
            int q   = idx >> 4;
            int k0l = (idx & 15) << 2;
            float4 v = *reinterpret_cast<const float4*>(
                &attn[((size_t)b * SS + q0 + q) * SS + (kc << 6) + k0l]);
            AsT[(k0l + 0) * 68 + q] = v.x;
            AsT[(k0l + 1) * 68 + q] = v.y;
            AsT[(k0l + 2) * 68 + q] = v.z;
            AsT[(k0l + 3) * 68 + q] = v.w;
        }
#pragma unroll
        for (int r = 0; r < 4; ++r) {
            int idx = tid + (r << 8);
            int kk = idx >> 4;
            int d0 = (idx & 15) << 2;
            float4 v = *reinterpret_cast<const float4*>(
                &V[((size_t)b * SS + (kc << 6) + kk) * ADIM + d0]);
            *reinterpret_cast<float4*>(&Vs[kk * 68 + d0]) = v;
        }
        __syncthreads();
#pragma unroll 16
        for (int kk = 0; kk < 64; ++kk) {
            float4 a  = *reinterpret_cast<const float4*>(&AsT[kk * 68 + (ty << 2)]);
            float4 vv = *reinterpret_cast<const float4*>(&Vs[kk * 68 + (tx << 2)]);
            const float aa[4] = {a.x, a.y, a.z, a.w};
            const float va[4] = {vv.x, vv.y, vv.z, vv.w};
#pragma unroll
            for (int i = 0; i < 4; ++i)
#pragma unroll
                for (int j = 0; j < 4; ++j)
                    t_acc[i][j] += aa[i] * va[j];
        }
    }
    __syncthreads();
#pragma unroll
    for (int i = 0; i < 4; ++i)
#pragma unroll
        for (int j = 0; j < 4; ++j)
            UsT[(tx << 2) + j][(ty << 2) + i] = t_acc[i][j];

    float o_acc[4][16];
#pragma unroll
    for (int i = 0; i < 4; ++i)
#pragma unroll
        for (int t = 0; t < 16; ++t) o_acc[i][t] = 0.f;

    for (int dc = 0; dc < 2; ++dc) {
        __syncthreads();
#pragma unroll
        for (int r = 0; r < 8; ++r) {
            int idx = tid + (r << 8);
            int dl = idx >> 6;
            int n0 = (idx & 63) << 2;
            float4 w = *reinterpret_cast<const float4*>(
                &Wh[((size_t)((dc << 5) + dl)) * HIDD + n0]);
            *reinterpret_cast<float4*>(&Whs[dl * 260 + n0]) = w;
        }
        __syncthreads();
#pragma unroll 8
        for (int dl = 0; dl < 32; ++dl) {
            float4 u = *reinterpret_cast<const float4*>(&UsT[(dc << 5) + dl][ty << 2]);
            const float ua[4] = {u.x, u.y, u.z, u.w};
#pragma unroll
            for (int jj = 0; jj < 4; ++jj) {
                float4 w = *reinterpret_cast<const float4*>(&Whs[dl * 260 + (jj << 6) + (tx << 2)]);
                const float wa[4] = {w.x, w.y, w.z, w.w};
#pragma unroll
                for (int i = 0; i < 4; ++i) {
                    o_acc[i][(jj << 2) + 0] += ua[i] * wa[0];
                    o_acc[i][(jj << 2) + 1] += ua[i] * wa[1];
                    o_acc[i][(jj << 2) + 2] += ua[i] * wa[2];
                    o_acc[i][(jj << 2) + 3] += ua[i] * wa[3];
                }
            }
        }
    }

#pragma unroll
    for (int i = 0; i < 4; ++i) {
        const int q = q0 + (ty << 2) + i;
#pragma unroll
        for (int jj = 0; jj < 4; ++jj) {
            const int n = (jj << 6) + (tx << 2);
            float4 bv4 = *reinterpret_cast<const float4*>(&bh[n]);
            float4 o;
            o.x = o_acc[i][(jj << 2) + 0] + bv4.x;
            o.y = o_acc[i][(jj << 2) + 1] + bv4.y;
            o.z = o_acc[i][(jj << 2) + 2] + bv4.z;
            o.w = o_acc[i][(jj << 2) + 3] + bv4.w;
            *reinterpret_cast<float4*>(&out[((size_t)b * SS + q) * HIDD + n]) = o;
        }
    }
}

// ---------------------------------------------------------------------------
extern "C" void kernel_launch(void* const* d_in, const int* in_sizes, int n_in,
                              void* d_out, int out_size, void* d_ws, size_t ws_size,
                              hipStream_t stream)
{
    const float* query = (const float*)d_in[0];
    const float* key   = (const float*)d_in[1];
    const float* value = (const float*)d_in[2];
    const int*   mask  = (const int*)d_in[3];
    const float* Wq = (const float*)d_in[4];
    const float* bq = (const float*)d_in[5];
    const float* Wk = (const float*)d_in[6];
    const float* bk = (const float*)d_in[7];
    const float* Wv = (const float*)d_in[8];
    const float* bv = (const float*)d_in[9];
    const float* Wh = (const float*)d_in[10];
    const float* bh = (const float*)d_in[11];

    float* out  = (float*)d_out;                       // [B,S,HID]
    float* attn = out + (size_t)NB * SS * HIDD;        // [B,S,S]

    const size_t BS = (size_t)NB * SS;
    short* Qhi = (short*)d_ws;                         // [BS, HID] bf16 bits
    short* Qlo = Qhi + BS * HIDD;
    short* Khi = Qlo + BS * HIDD;
    short* Klo = Khi + BS * HIDD;
    float* Vp  = (float*)(Klo + BS * HIDD);            // [BS, ADIM] fp32

    gemm_bias_split<<<dim3(512, 4), 256, 0, stream>>>(query, Wq, bq, Qhi, Qlo, NB * SS, HIDD, HIDD);
    gemm_bias_split<<<dim3(512, 4), 256, 0, stream>>>(key,   Wk, bk, Khi, Klo, NB * SS, HIDD, HIDD);
    gemm_bias<<<dim3(512, 1), 256, 0, stream>>>(value, Wv, bv, Vp, NB * SS, HIDD, ADIM);
    attn_probs_mfma<<<dim3(1024), 256, 0, stream>>>(Qhi, Qlo, Khi, Klo, mask, attn);
    attn_out_kernel<<<dim3(64, 8), 256, 0, stream>>>(attn, Vp, Wh, bh, out);
}